// Round 1
// baseline (637.584 us; speedup 1.0000x reference)
//
#include <hip/hip_runtime.h>
#include <math.h>

// Problem constants (from reference): x is (8, 4096, 3*1024) fp32.
#define BATCH 8
#define TLEN  4096
#define DH    1024
#define ROW   (3 * DH)          // 3072 floats per (b,t) row
#define EPS   1e-4f
#define CHUNK 64                // steps per chunk
#define NCHUNK (TLEN / CHUNK)   // 64
#define NLANE (BATCH * DH)      // 8192 independent scan lanes

// fast sigmoid / tanh — absmax tolerance is 1.3e-2, __expf (v_exp_f32) is
// plenty accurate (~2 ulp). Formulas saturate correctly at +/-inf.
__device__ __forceinline__ float fsigmoid(float z) {
    return 1.0f / (1.0f + __expf(-z));
}
__device__ __forceinline__ float ftanh(float v) {
    return 1.0f - 2.0f / (__expf(2.0f * v) + 1.0f);
}

// K1: per-(lane, chunk) product of forget gates.
// f_t = 1 - sigmoid(x_i) = 1/(1+exp(x_i)), x_i = x[b, t, DH + d]
__global__ void k_chunkprod(const float* __restrict__ x, float* __restrict__ P) {
    const int d = blockIdx.x * blockDim.x + threadIdx.x;  // 0..1023
    const int b = blockIdx.y;
    const int c = blockIdx.z;
    const float* xg = x + (size_t)(b * TLEN + c * CHUNK) * ROW + DH + d;
    float p = 1.0f;
#pragma unroll 8
    for (int t = 0; t < CHUNK; ++t) {
        float z = xg[(size_t)t * ROW];
        p *= 1.0f / (1.0f + __expf(z));
    }
    P[c * NLANE + b * DH + d] = p;
}

// K2: per-lane exclusive scan of chunk products -> incoming cumprod a_in.
__global__ void k_scan_a(const float* __restrict__ P, float* __restrict__ Ain) {
    const int lane = blockIdx.x * blockDim.x + threadIdx.x;  // 0..8191
    float a = 1.0f;
#pragma unroll 8
    for (int c = 0; c < NCHUNK; ++c) {
        Ain[c * NLANE + lane] = a;
        a *= P[c * NLANE + lane];
    }
}

// K3: per-(lane, chunk) local recurrence with y_in = 0 given a_in -> Q.
// y_t = f_t*y_{t-1} + kv_t * a_t/(a_t+eps)
__global__ void k_partial(const float* __restrict__ x,
                          const float* __restrict__ Ain,
                          float* __restrict__ Q) {
    const int d = blockIdx.x * blockDim.x + threadIdx.x;
    const int b = blockIdx.y;
    const int c = blockIdx.z;
    const int lane = b * DH + d;
    const float* xp = x + (size_t)(b * TLEN + c * CHUNK) * ROW + d;
    float a = Ain[c * NLANE + lane];
    float y = 0.0f;
#pragma unroll 4
    for (int t = 0; t < CHUNK; ++t) {
        const float* row = xp + (size_t)t * ROW;
        float zx = row[0];
        float zi = row[DH];
        float f  = 1.0f / (1.0f + __expf(zi));  // forget gate = 1 - sigmoid(zi)
        float ig = 1.0f - f;                    // input gate
        float kv = ftanh(zx) * ig;
        a *= f;
        float r = a / (a + EPS);
        y = f * y + kv * r;
    }
    Q[c * NLANE + lane] = y;
}

// K4: per-lane exclusive scan of (P, Q) -> incoming y per chunk.
__global__ void k_scan_y(const float* __restrict__ P,
                         const float* __restrict__ Q,
                         float* __restrict__ Yin) {
    const int lane = blockIdx.x * blockDim.x + threadIdx.x;
    float y = 0.0f;
#pragma unroll 8
    for (int c = 0; c < NCHUNK; ++c) {
        Yin[c * NLANE + lane] = y;
        y = P[c * NLANE + lane] * y + Q[c * NLANE + lane];
    }
}

// K5: recompute chunk with known (a_in, y_in); apply output gate, write out.
__global__ void k_final(const float* __restrict__ x,
                        const float* __restrict__ Ain,
                        const float* __restrict__ Yin,
                        float* __restrict__ out) {
    const int d = blockIdx.x * blockDim.x + threadIdx.x;
    const int b = blockIdx.y;
    const int c = blockIdx.z;
    const int lane = b * DH + d;
    const float* xp = x + (size_t)(b * TLEN + c * CHUNK) * ROW + d;
    float* op = out + (size_t)(b * TLEN + c * CHUNK) * DH + d;
    float a = Ain[c * NLANE + lane];
    float y = Yin[c * NLANE + lane];
#pragma unroll 4
    for (int t = 0; t < CHUNK; ++t) {
        const float* row = xp + (size_t)t * ROW;
        float zx = row[0];
        float zi = row[DH];
        float zo = row[2 * DH];
        float f  = 1.0f / (1.0f + __expf(zi));
        float ig = 1.0f - f;
        float kv = ftanh(zx) * ig;
        a *= f;
        float r = a / (a + EPS);
        y = f * y + kv * r;
        float og = fsigmoid(zo);
        op[(size_t)t * DH] = ftanh(y) * og;
    }
}

extern "C" void kernel_launch(void* const* d_in, const int* in_sizes, int n_in,
                              void* d_out, int out_size, void* d_ws, size_t ws_size,
                              hipStream_t stream) {
    const float* x = (const float*)d_in[0];
    float* out = (float*)d_out;

    // Workspace layout: 4 buffers of NCHUNK*NLANE fp32 = 4 * 2 MB = 8 MB.
    float* P   = (float*)d_ws;
    float* Ain = P   + (size_t)NCHUNK * NLANE;
    float* Q   = Ain + (size_t)NCHUNK * NLANE;
    float* Yin = Q   + (size_t)NCHUNK * NLANE;

    dim3 blk(256);
    dim3 grd(DH / 256, BATCH, NCHUNK);   // 4 x 8 x 64 = 2048 blocks
    dim3 sblk(256);
    dim3 sgrd(NLANE / 256);              // 32 blocks

    k_chunkprod<<<grd, blk, 0, stream>>>(x, P);
    k_scan_a<<<sgrd, sblk, 0, stream>>>(P, Ain);
    k_partial<<<grd, blk, 0, stream>>>(x, Ain, Q);
    k_scan_y<<<sgrd, sblk, 0, stream>>>(P, Q, Yin);
    k_final<<<grd, blk, 0, stream>>>(x, Ain, Yin, out);
}